// Round 6
// baseline (358.110 us; speedup 1.0000x reference)
//
#include <hip/hip_runtime.h>

// GCN 2-layer forward for MI355X.
// R6: gemm1 8-wave (16x64 wave tile) to spread fp32->fp16-split VALU and
// raise occupancy; full XOR swizzle (^(r&3)^((r>>2)&3)) kills residual 4-way
// LDS conflicts; agg kernels use float4 lanes + multi-node waves for 2-4x
// memory-level parallelism; CSR packed as int2 (one 8B load per edge).

#define NNODES 50000
#define NEDGES 640000
#define NFEAT 512
#define NHID 128
#define NCLS 64

typedef _Float16 f16x8 __attribute__((ext_vector_type(8)));
typedef _Float16 f16x4 __attribute__((ext_vector_type(4)));
typedef float f32x4 __attribute__((ext_vector_type(4)));

__device__ __forceinline__ void g2l16(const void* g, void* s) {
  __builtin_amdgcn_global_load_lds(
      (const __attribute__((address_space(1))) void*)g,
      (__attribute__((address_space(3))) void*)s, 16, 0, 0);
}

__global__ void k_zero2(int* __restrict__ a, int* __restrict__ b, int n) {
  int i = blockIdx.x * blockDim.x + threadIdx.x;
  if (i < n) { a[i] = 0; b[i] = 0; }
}

__global__ void k_hist(const int* __restrict__ dst, int* __restrict__ indeg, int E) {
  int i = blockIdx.x * blockDim.x + threadIdx.x;
  if (i < E) atomicAdd(&indeg[dst[i]], 1);
}

// Exclusive scan over n+1 slots of PADDED degree ((d+3)&~3); also emits dinv.
__global__ void k_scan_block(const int* __restrict__ indeg, float* __restrict__ dinv,
                             int* __restrict__ row_start, int* __restrict__ blocksum,
                             int n) {
  __shared__ int sdata[256];
  int t = threadIdx.x;
  int base = blockIdx.x * 1024 + t * 4;
  int v[4];
#pragma unroll
  for (int j = 0; j < 4; ++j) {
    int idx = base + j;
    int d = (idx < n) ? indeg[idx] : 0;
    if (idx < n) dinv[idx] = 1.0f / sqrtf((float)(d + 1));
    v[j] = (d + 3) & ~3;
  }
  int tsum = v[0] + v[1] + v[2] + v[3];
  sdata[t] = tsum;
  __syncthreads();
  for (int off = 1; off < 256; off <<= 1) {
    int x = (t >= off) ? sdata[t - off] : 0;
    __syncthreads();
    sdata[t] += x;
    __syncthreads();
  }
  int excl = sdata[t] - tsum;
  if (t == 255) blocksum[blockIdx.x] = sdata[255];
  int run = excl;
#pragma unroll
  for (int j = 0; j < 4; ++j) {
    if (base + j <= n) { row_start[base + j] = run; run += v[j]; }
  }
}

__global__ void k_scan_top(const int* __restrict__ blocksum, int* __restrict__ blockoff, int nb) {
  if (threadIdx.x == 0 && blockIdx.x == 0) {
    int run = 0;
    for (int i = 0; i < nb; ++i) { blockoff[i] = run; run += blocksum[i]; }
  }
}

// Finalize row_start and fill padding slots (src=self, norm=0).
__global__ void k_scan_add(int* __restrict__ row_start, const int* __restrict__ blockoff,
                           const int* __restrict__ indeg, int2* __restrict__ csr,
                           int n) {
  int i = blockIdx.x * blockDim.x + threadIdx.x;
  if (i <= n) {
    int rs = row_start[i] + blockoff[i >> 10];
    row_start[i] = rs;
    if (i < n) {
      int d = indeg[i];
      int p = (d + 3) & ~3;
      for (int j = d; j < p; ++j) csr[rs + j] = make_int2(i, 0);
    }
  }
}

__global__ void k_scatter(const int* __restrict__ src, const int* __restrict__ dst,
                          const int* __restrict__ row_start, int* __restrict__ cursor,
                          const float* __restrict__ dinv, int2* __restrict__ csr, int E) {
  int e = blockIdx.x * blockDim.x + threadIdx.x;
  if (e < E) {
    int s = src[e], d = dst[e];
    int pos = atomicAdd(&cursor[d], 1);
    float w = dinv[s] * dinv[d];
    csr[row_start[d] + pos] = make_int2(s, __float_as_int(w));
  }
}

// W [K][Nc] fp32 -> transposed fp16 split: Wt_hi/Wt_lo [Nc][K], lo pre-scaled 1024.
__global__ void k_wcvt(const float* __restrict__ W, _Float16* __restrict__ Wt_hi,
                       _Float16* __restrict__ Wt_lo, int K, int Nc) {
  int i = blockIdx.x * blockDim.x + threadIdx.x;
  if (i < K * Nc) {
    int k = i / Nc, n = i % Nc;
    float v = W[i];
    _Float16 h = (_Float16)v;
    Wt_hi[(size_t)n * K + k] = h;
    Wt_lo[(size_t)n * K + k] = (_Float16)((v - (float)h) * 1024.0f);
  }
}

// GEMM1: C[M][128] = A[M][512] fp32 @ W1 (Bt split [128][512] f16).
// 512 thr / 8 waves (4My x 2Nx), block tile 64x128, wave tile 16x64, BK=32.
// LDS 48KB: A[2] fp32 [64][32] (slot XOR r&7), Bhi/Blo[2] f16 [128][32]
// (slot XOR (n&3)^((n>>2)&3) -> 2-way max). global_load_lds, src pre-swizzled.
__global__ __launch_bounds__(512, 6) void k_gemm1(const float* __restrict__ A,
                                                  const _Float16* __restrict__ Bhi,
                                                  const _Float16* __restrict__ Blo,
                                                  float* __restrict__ C, int M) {
  __shared__ char smem[49152];
  constexpr int A_OFF = 0;       // 2 x 8KB
  constexpr int BH_OFF = 16384;  // 2 x 8KB
  constexpr int BL_OFF = 32768;  // 2 x 8KB
  const int tid = threadIdx.x;
  const int wid = tid >> 6, lane = tid & 63;
  const int wy = wid >> 1, wx = wid & 1;
  const int row0 = blockIdx.x * 64;
  const int lrow = lane & 15;
  const int lkg = lane >> 4;  // k-octet group 0..3

  auto stage = [&](int buf, int k0) {
    {
      int row = tid >> 3;                 // 0..63
      int kq = (tid & 7) ^ (row & 7);     // 16B slot in 128B row
      int gr = row0 + row; gr = gr < M ? gr : M - 1;
      g2l16((const char*)A + (size_t)gr * 2048 + (size_t)k0 * 4 + kq * 16,
            smem + A_OFF + buf * 8192 + ((tid & ~63) << 4));
    }
    {
      int n = tid >> 2;                                  // 0..127
      int kq = (tid & 3) ^ (n & 3) ^ ((n >> 2) & 3);     // 16B slot in 64B row
      size_t so = (size_t)n * 1024 + (size_t)k0 * 2 + kq * 16;
      g2l16((const char*)Bhi + so, smem + BH_OFF + buf * 8192 + ((tid & ~63) << 4));
      g2l16((const char*)Blo + so, smem + BL_OFF + buf * 8192 + ((tid & ~63) << 4));
    }
  };

  f32x4 acc_h[4] = {};
  f32x4 acc_l[4] = {};

  stage(0, 0);
  __syncthreads();
  int cur = 0;
  constexpr int NK = NFEAT / 32;  // 16
  for (int ks = 0; ks < NK; ++ks) {
    if (ks + 1 < NK) stage(cur ^ 1, (ks + 1) * 32);

    const char* ab = smem + A_OFF + cur * 8192;
    const char* bhb = smem + BH_OFF + cur * 8192;
    const char* blb = smem + BL_OFF + cur * 8192;
    f16x8 ah, al, bh[4], bl[4];
    {
      int r = wy * 16 + lrow;
      int lin = r * 128 + lkg * 32;
      int sw = (r & 7) << 4;
      float4 v0 = *(const float4*)(ab + (lin ^ sw));
      float4 v1 = *(const float4*)(ab + ((lin + 16) ^ sw));
      float vv[8] = {v0.x, v0.y, v0.z, v0.w, v1.x, v1.y, v1.z, v1.w};
#pragma unroll
      for (int j = 0; j < 8; ++j) {
        _Float16 h = (_Float16)vv[j];
        ah[j] = h;
        al[j] = (_Float16)((vv[j] - (float)h) * 1024.0f);
      }
    }
#pragma unroll
    for (int cf = 0; cf < 4; ++cf) {
      int n = wx * 64 + cf * 16 + lrow;
      int slot = lkg ^ (n & 3) ^ ((n >> 2) & 3);
      int lin = n * 64 + slot * 16;
      bh[cf] = *(const f16x8*)(bhb + lin);
      bl[cf] = *(const f16x8*)(blb + lin);
    }
#pragma unroll
    for (int cf = 0; cf < 4; ++cf) {
      acc_h[cf] = __builtin_amdgcn_mfma_f32_16x16x32_f16(ah, bh[cf], acc_h[cf], 0, 0, 0);
      acc_l[cf] = __builtin_amdgcn_mfma_f32_16x16x32_f16(ah, bl[cf], acc_l[cf], 0, 0, 0);
      acc_l[cf] = __builtin_amdgcn_mfma_f32_16x16x32_f16(al, bh[cf], acc_l[cf], 0, 0, 0);
    }
    if (ks + 1 < NK) { __syncthreads(); cur ^= 1; }
  }

  int rfrag = row0 + wy * 16;
  if (rfrag < M) {  // M % 16 == 0: frag all-valid or all-invalid
    int rbase = rfrag + lkg * 4;
#pragma unroll
    for (int cf = 0; cf < 4; ++cf) {
      int col = wx * 64 + cf * 16 + lrow;
#pragma unroll
      for (int q = 0; q < 4; ++q)
        C[(size_t)(rbase + q) * NHID + col] =
            acc_h[cf][q] + acc_l[cf][q] * (1.0f / 1024.0f);
    }
  }
}

// GEMM2: C[M][64] = h1 (fp16 pair [M][128]) @ W2 (Bt split [64][128]).
// 256 thr / 4 waves stacked in M, block tile 64x64, wave tile 16x64, BK=32.
// LDS 32KB, slot XOR (r&3)^((r>>2)&3) everywhere.
__global__ __launch_bounds__(256) void k_gemm2(const _Float16* __restrict__ Ahi,
                                               const _Float16* __restrict__ Alo,
                                               const _Float16* __restrict__ Bhi,
                                               const _Float16* __restrict__ Blo,
                                               float* __restrict__ C, int M) {
  __shared__ char smem[32768];
  constexpr int AH_OFF = 0;      // 2 x 4KB
  constexpr int AL_OFF = 8192;   // 2 x 4KB
  constexpr int BH_OFF = 16384;  // 2 x 4KB
  constexpr int BL_OFF = 24576;  // 2 x 4KB
  const int tid = threadIdx.x;
  const int wid = tid >> 6, lane = tid & 63;
  const int row0 = blockIdx.x * 64;
  const int lrow = lane & 15;
  const int lkg = lane >> 4;

  auto stage = [&](int buf, int k0) {
    int row = tid >> 2;  // 0..63
    int kq = (tid & 3) ^ (row & 3) ^ ((row >> 2) & 3);
    int gr = row0 + row; gr = gr < M ? gr : M - 1;
    size_t aso = (size_t)gr * 256 + (size_t)k0 * 2 + kq * 16;
    size_t bso = (size_t)row * 256 + (size_t)k0 * 2 + kq * 16;
    int ldso = (tid & ~63) << 4;
    g2l16((const char*)Ahi + aso, smem + AH_OFF + buf * 4096 + ldso);
    g2l16((const char*)Alo + aso, smem + AL_OFF + buf * 4096 + ldso);
    g2l16((const char*)Bhi + bso, smem + BH_OFF + buf * 4096 + ldso);
    g2l16((const char*)Blo + bso, smem + BL_OFF + buf * 4096 + ldso);
  };

  f32x4 acc_h[4] = {};
  f32x4 acc_l[4] = {};

  stage(0, 0);
  __syncthreads();
  int cur = 0;
  constexpr int NK = NHID / 32;  // 4
  for (int ks = 0; ks < NK; ++ks) {
    if (ks + 1 < NK) stage(cur ^ 1, (ks + 1) * 32);

    const char* ahb = smem + AH_OFF + cur * 4096;
    const char* alb = smem + AL_OFF + cur * 4096;
    const char* bhb = smem + BH_OFF + cur * 4096;
    const char* blb = smem + BL_OFF + cur * 4096;
    int r = wid * 16 + lrow;
    int aslot = lkg ^ (r & 3) ^ ((r >> 2) & 3);
    int alin = r * 64 + aslot * 16;
    f16x8 ah = *(const f16x8*)(ahb + alin);
    f16x8 al = *(const f16x8*)(alb + alin);
    f16x8 bh[4], bl[4];
#pragma unroll
    for (int cf = 0; cf < 4; ++cf) {
      int n = cf * 16 + lrow;
      int slot = lkg ^ (n & 3) ^ ((n >> 2) & 3);
      int lin = n * 64 + slot * 16;
      bh[cf] = *(const f16x8*)(bhb + lin);
      bl[cf] = *(const f16x8*)(blb + lin);
    }
#pragma unroll
    for (int cf = 0; cf < 4; ++cf) {
      acc_h[cf] = __builtin_amdgcn_mfma_f32_16x16x32_f16(ah, bh[cf], acc_h[cf], 0, 0, 0);
      acc_l[cf] = __builtin_amdgcn_mfma_f32_16x16x32_f16(ah, bl[cf], acc_l[cf], 0, 0, 0);
      acc_l[cf] = __builtin_amdgcn_mfma_f32_16x16x32_f16(al, bh[cf], acc_l[cf], 0, 0, 0);
    }
    if (ks + 1 < NK) { __syncthreads(); cur ^= 1; }
  }

  int rfrag = row0 + wid * 16;
  if (rfrag < M) {
    int rbase = rfrag + lkg * 4;
#pragma unroll
    for (int cf = 0; cf < 4; ++cf) {
      int col = cf * 16 + lrow;
#pragma unroll
      for (int q = 0; q < 4; ++q)
        C[(size_t)(rbase + q) * NCLS + col] =
            acc_h[cf][q] + acc_l[cf][q] * (1.0f / 1024.0f);
    }
  }
}

// agg F=128: half-wave (32 lanes) per node, float4 lanes, 8-deep unroll.
// 256 thr -> 8 nodes/block. N % 8 == 0 handled by guard.
template <bool RELU, bool EMIT16>
__global__ __launch_bounds__(256) void k_agg128(
    const float* __restrict__ h, const float* __restrict__ bias,
    const int* __restrict__ row_start, const int2* __restrict__ csr,
    const float* __restrict__ dinv, float* __restrict__ out,
    _Float16* __restrict__ out_hi, _Float16* __restrict__ out_lo, int N) {
  int tid = threadIdx.x;
  int lane = tid & 63;
  int node = blockIdx.x * 8 + (tid >> 6) * 2 + (lane >> 5);
  if (node >= N) return;
  int li = lane & 31;

  float dn = dinv[node];
  f32x4 bs = *(const f32x4*)(bias + li * 4);
  f32x4 sf = *(const f32x4*)(h + (size_t)node * 128 + li * 4);
  f32x4 a0 = dn * dn * sf + bs;
  f32x4 a1 = {}, a2 = {}, a3 = {}, a4 = {}, a5 = {}, a6 = {}, a7 = {};

  int e = row_start[node], e1 = row_start[node + 1];
#define GATH(ACC, EI)                                              \
  {                                                                \
    int2 p_ = csr[EI];                                             \
    float w_ = __int_as_float(p_.y);                               \
    f32x4 v_ = *(const f32x4*)(h + (size_t)p_.x * 128 + li * 4);   \
    ACC += w_ * v_;                                                \
  }
  for (; e + 8 <= e1; e += 8) {
    GATH(a0, e + 0) GATH(a1, e + 1) GATH(a2, e + 2) GATH(a3, e + 3)
    GATH(a4, e + 4) GATH(a5, e + 5) GATH(a6, e + 6) GATH(a7, e + 7)
  }
  if (e < e1) {  // exactly 4 remain (padded count % 4 == 0)
    GATH(a0, e + 0) GATH(a1, e + 1) GATH(a2, e + 2) GATH(a3, e + 3)
  }
#undef GATH
  f32x4 acc = ((a0 + a1) + (a2 + a3)) + ((a4 + a5) + (a6 + a7));
  if (RELU) {
#pragma unroll
    for (int j = 0; j < 4; ++j) acc[j] = fmaxf(acc[j], 0.f);
  }
  if (EMIT16) {
    f16x4 vh, vl;
#pragma unroll
    for (int j = 0; j < 4; ++j) {
      _Float16 hh = (_Float16)acc[j];
      vh[j] = hh;
      vl[j] = (_Float16)((acc[j] - (float)hh) * 1024.0f);
    }
    *(f16x4*)(out_hi + (size_t)node * 128 + li * 4) = vh;
    *(f16x4*)(out_lo + (size_t)node * 128 + li * 4) = vl;
  } else {
    *(f32x4*)(out + (size_t)node * 128 + li * 4) = acc;
  }
}

// agg F=64: quarter-wave (16 lanes) per node, float4 lanes, 8-deep unroll.
// 256 thr -> 16 nodes/block.
__global__ __launch_bounds__(256) void k_agg64(
    const float* __restrict__ h, const float* __restrict__ bias,
    const int* __restrict__ row_start, const int2* __restrict__ csr,
    const float* __restrict__ dinv, float* __restrict__ out, int N) {
  int tid = threadIdx.x;
  int lane = tid & 63;
  int node = blockIdx.x * 16 + (tid >> 6) * 4 + (lane >> 4);
  if (node >= N) return;
  int li = lane & 15;

  float dn = dinv[node];
  f32x4 bs = *(const f32x4*)(bias + li * 4);
  f32x4 sf = *(const f32x4*)(h + (size_t)node * 64 + li * 4);
  f32x4 a0 = dn * dn * sf + bs;
  f32x4 a1 = {}, a2 = {}, a3 = {}, a4 = {}, a5 = {}, a6 = {}, a7 = {};

  int e = row_start[node], e1 = row_start[node + 1];
#define GATH(ACC, EI)                                             \
  {                                                               \
    int2 p_ = csr[EI];                                            \
    float w_ = __int_as_float(p_.y);                              \
    f32x4 v_ = *(const f32x4*)(h + (size_t)p_.x * 64 + li * 4);   \
    ACC += w_ * v_;                                               \
  }
  for (; e + 8 <= e1; e += 8) {
    GATH(a0, e + 0) GATH(a1, e + 1) GATH(a2, e + 2) GATH(a3, e + 3)
    GATH(a4, e + 4) GATH(a5, e + 5) GATH(a6, e + 6) GATH(a7, e + 7)
  }
  if (e < e1) {
    GATH(a0, e + 0) GATH(a1, e + 1) GATH(a2, e + 2) GATH(a3, e + 3)
  }
#undef GATH
  f32x4 acc = ((a0 + a1) + (a2 + a3)) + ((a4 + a5) + (a6 + a7));
  *(f32x4*)(out + (size_t)node * 64 + li * 4) = acc;
}

static inline size_t align256(size_t x) { return (x + 255) & ~(size_t)255; }

extern "C" void kernel_launch(void* const* d_in, const int* in_sizes, int n_in,
                              void* d_out, int out_size, void* d_ws, size_t ws_size,
                              hipStream_t stream) {
  const float* x = (const float*)d_in[0];
  const int* edge = (const int*)d_in[1];
  const float* W1 = (const float*)d_in[2];
  const float* b1 = (const float*)d_in[3];
  const float* W2 = (const float*)d_in[4];
  const float* b2 = (const float*)d_in[5];
  float* out = (float*)d_out;

  const int N = NNODES;
  const int E = NEDGES;
  const int EPAD = E + 3 * N + 256;
  const int* src = edge;
  const int* dst = edge + E;

  char* w = (char*)d_ws;
  int* indeg = (int*)w;            w += align256((size_t)N * 4);
  int* cursor = (int*)w;           w += align256((size_t)N * 4);
  float* dinv = (float*)w;         w += align256((size_t)N * 4);
  int* row_start = (int*)w;        w += align256((size_t)(N + 1) * 4);
  int* blocksum = (int*)w;         w += align256(64 * 4);
  int* blockoff = (int*)w;         w += align256(64 * 4);
  int2* csr = (int2*)w;            w += align256((size_t)EPAD * 8);
  _Float16* W1t_hi = (_Float16*)w; w += align256((size_t)NFEAT * NHID * 2);
  _Float16* W1t_lo = (_Float16*)w; w += align256((size_t)NFEAT * NHID * 2);
  _Float16* W2t_hi = (_Float16*)w; w += align256((size_t)NHID * NCLS * 2);
  _Float16* W2t_lo = (_Float16*)w; w += align256((size_t)NHID * NCLS * 2);
  float* h0 = (float*)w;           w += align256((size_t)N * NHID * 4);
  _Float16* h1_hi = (_Float16*)w;  w += align256((size_t)N * NHID * 2);
  _Float16* h1_lo = (_Float16*)w;  w += align256((size_t)N * NHID * 2);
  float* h2 = (float*)w;           w += align256((size_t)N * NCLS * 4);

  const int nblk_n = (N + 255) / 256;
  const int nblk_n1 = (N + 1 + 255) / 256;
  const int nblk_e = (E + 255) / 256;
  const int nblk_scan = (N + 1 + 1023) / 1024;

  k_zero2<<<nblk_n, 256, 0, stream>>>(indeg, cursor, N);
  k_hist<<<nblk_e, 256, 0, stream>>>(dst, indeg, E);
  k_scan_block<<<nblk_scan, 256, 0, stream>>>(indeg, dinv, row_start, blocksum, N);
  k_scan_top<<<1, 64, 0, stream>>>(blocksum, blockoff, nblk_scan);
  k_scan_add<<<nblk_n1, 256, 0, stream>>>(row_start, blockoff, indeg, csr, N);
  k_scatter<<<nblk_e, 256, 0, stream>>>(src, dst, row_start, cursor, dinv, csr, E);

  k_wcvt<<<(NFEAT * NHID + 255) / 256, 256, 0, stream>>>(W1, W1t_hi, W1t_lo,
                                                         NFEAT, NHID);
  k_wcvt<<<(NHID * NCLS + 255) / 256, 256, 0, stream>>>(W2, W2t_hi, W2t_lo,
                                                        NHID, NCLS);

  // GEMM1: h0 = x @ W1 (782 blocks x 512 thr)
  k_gemm1<<<(N + 63) / 64, 512, 0, stream>>>(x, W1t_hi, W1t_lo, h0, N);
  // agg1: h1 = relu(Ahat*h0 + b1) -> fp16 split pair
  k_agg128<true, true><<<(N + 7) / 8, 256, 0, stream>>>(
      h0, b1, row_start, csr, dinv, nullptr, h1_hi, h1_lo, N);
  // GEMM2: h2 = h1 @ W2 (782 blocks)
  k_gemm2<<<(N + 63) / 64, 256, 0, stream>>>(h1_hi, h1_lo, W2t_hi, W2t_lo, h2, N);
  // agg2: out = Ahat*h2 + b2
  k_agg64<<<(N + 15) / 16, 256, 0, stream>>>(h2, b2, row_start, csr, dinv, out, N);
}